// Round 5
// baseline (1713.701 us; speedup 1.0000x reference)
//
#include <hip/hip_runtime.h>
#include <stdint.h>

// Net_11587821765063: sequential SNN scan, T=1000 steps.
// Output = spike_out (T,1,COUT) float32 only; w / traces are not returned.
//
// Math reductions (absmax 0 in rounds 1-4):
//  - potentiation p[t][i] = 2 if x[t][i] else (1 if (t==0 or x[t-1][i]) else 0)
//  - depression for row o at t = -x[t][i] iff (!spike[t][o] && spike[t-1][o]),
//    spike[-1] := true (cout init quirk).
//  - prohibit P[t] = 1 iff any spike at t-1 (grid-wide 1-bit OR); P[0]=0.
//
// Round 5: 2-step prohibit speculation. Each block publishes 4 hypothesis
// bits per step u: any-own-row-spike under (P[u-1]=d, P[u]=c), bit k=(d<<1)|c.
// Line(u) is gathered at iteration u+2 (two iterations of slack) and the
// recurrence  P[u-1] = A(u-2)[P[u-3]][P[u-2]]  is resolved by wave0 BEFORE
// the single per-step barrier (gather load issued at iteration start, hidden
// behind the dot compute). Each wave keeps TWO branch states (weights,
// membrane, prev-spike) for P-branch 0/1; outputs lag one step.
// 32 blocks x 512 threads (8 waves, 2 rows/wave, 13 cols/lane in regs).
// All FP sequences (per-lane dot order, xor32..1 reduction tree, membrane
// and clamp ops) are bit-identical to the rounds-1..4 validated ones.

#define T_STEPS 1000
#define CIN     784
#define COUT    512
#define CPL     13            // columns per lane (64*13 = 832 >= 784)
#define NBLK    32
#define WPB     8             // waves per block
#define RPW     2             // rows per wave (16 rows/block)
#define VTHR_F   12500.0f
#define PROHIB_F 11250.0f

#define SLOTS_WORDS (T_STEPS * NBLK)          // uint32 per (u, blk)
#define CODE_OFFSET 524288                    // 512 KiB, 16B-aligned

// ---- prep: zero slot words and pack per-(t,lane) 16-byte code slot:
// byte j (j<13) encodes col = lane*13+j: bit0 = x[t][col], bits[2:1] = p.
__global__ __launch_bounds__(256) void prep_kernel(const int* __restrict__ x,
                                                   uint8_t* __restrict__ code,
                                                   uint32_t* __restrict__ slots) {
    int gid = blockIdx.x * blockDim.x + threadIdx.x;   // one per (t, lane)
    if (gid >= T_STEPS * 64) return;
    if (gid < SLOTS_WORDS) slots[gid] = 0u;            // 32000 dwords
    int t = gid >> 6;
    int lane = gid & 63;
    uint32_t wds[4] = {0u, 0u, 0u, 0u};
    #pragma unroll
    for (int j = 0; j < CPL; ++j) {
        int col = lane * CPL + j;
        uint32_t b = 0u;
        if (col < CIN) {
            int xc = x[t * CIN + col];
            int xp = (t > 0) ? x[(t - 1) * CIN + col] : 0;
            int p = xc ? 2 : ((t == 0) ? 1 : (xp ? 1 : 0));
            b = (uint32_t)((xc & 1) | (p << 1));
        }
        wds[j >> 2] |= b << ((j & 3) * 8);
    }
    ((uint4*)code)[gid] = make_uint4(wds[0], wds[1], wds[2], wds[3]);
}

__global__ __launch_bounds__(512) void snn_kernel(const float* __restrict__ weight,
                                                  const uint8_t* __restrict__ code,
                                                  uint32_t* __restrict__ slots,
                                                  float* __restrict__ out) {
    __shared__ int sh_h[2][WPB];    // double-buffered per-wave hypothesis bits
    __shared__ int sh_b[2];         // double-buffered resolved branch bit

    const int tid  = threadIdx.x;
    const int wave = tid >> 6;
    const int lane = tid & 63;
    const int blk  = blockIdx.x;
    const int row0 = blk * (WPB * RPW) + wave * RPW;

    // two branch weight states (branch = hypothesis of the latest unresolved P)
    float wA[RPW][CPL], wB[RPW][CPL];
    #pragma unroll
    for (int r = 0; r < RPW; ++r)
        #pragma unroll
        for (int j = 0; j < CPL; ++j) {
            int col = lane * CPL + j;
            float v = (col < CIN) ? weight[(row0 + r) * CIN + col] : 0.0f;
            wA[r][j] = v;
            wB[r][j] = v;
        }

    const uint4* code4 = (const uint4*)code;
    uint4 cw  = code4[lane];               // codes for u=0
    uint4 cwn = code4[64 + lane];          // codes for u=1 (prefetch)

    float memA[RPW] = {0.0f, 0.0f}, memB[RPW] = {0.0f, 0.0f};
    bool  psA[RPW]  = {true, true},  psB[RPW]  = {true, true};  // spike(-1)=true quirk
    int p2 = 0, p3 = 0;                    // wave0: actual P[u-2], P[u-3]

    for (int u = 0; u < T_STEPS; ++u) {
        // ---- wave0: early prefetch of line(u-2) (use is ~800 cyc later) ----
        const uint32_t* gl = slots + (size_t)(u >= 2 ? u - 2 : 0) * NBLK;
        uint32_t gv = 0xB0u;
        if (wave == 0 && u >= 2 && lane < NBLK)
            gv = __hip_atomic_load(&gl[lane], __ATOMIC_RELAXED,
                                   __HIP_MEMORY_SCOPE_AGENT);

        // ---- decode codes for step u ----
        uint32_t cwd[4] = {cw.x, cw.y, cw.z, cw.w};
        float xf[CPL], pf[CPL];
        #pragma unroll
        for (int j = 0; j < CPL; ++j) {
            uint32_t c = (cwd[j >> 2] >> ((j & 3) * 8)) & 0xFFu;
            xf[j] = (float)(c & 1u);
            pf[j] = (float)(c >> 1);
        }

        // ---- two dots per row (branch A / branch B weights) ----
        float dA[RPW], dB[RPW];
        #pragma unroll
        for (int r = 0; r < RPW; ++r) {
            float a = 0.0f, b = 0.0f;
            #pragma unroll
            for (int j = 0; j < CPL; ++j) {
                a += xf[j] * wA[r][j];     // exact: x in {0,1}
                b += xf[j] * wB[r][j];
            }
            dA[r] = a; dB[r] = b;
        }

        // ---- folded reduction of 4 sums; tree identical to xor32..1 butterfly
        // value index q: 0->dA0 1->dA1 2->dB0 3->dB1
        bool half = (lane & 32) != 0;
        float kx = half ? dB[0] : dA[0];
        float ky = half ? dB[1] : dA[1];
        float sx = half ? dA[0] : dB[0];
        float sy = half ? dA[1] : dB[1];
        kx += __shfl_xor(sx, 32, 64);
        ky += __shfl_xor(sy, 32, 64);
        bool subq = (lane & 16) != 0;
        float kk = subq ? ky : kx;
        float ss = subq ? kx : ky;
        kk += __shfl_xor(ss, 16, 64);
        kk += __shfl_xor(kk, 8, 64);
        kk += __shfl_xor(kk, 4, 64);
        kk += __shfl_xor(kk, 2, 64);
        kk += __shfl_xor(kk, 1, 64);
        // broadcast: lane in quarter q holds kk=S_q, b1=S_{q^1}, b2=S_{q^2}, b3=S_{q^3}
        float b1 = __shfl_xor(kk, 16, 64);
        float b2 = __shfl_xor(kk, 32, 64);
        float b3 = __shfl_xor(b1, 32, 64);
        int q = lane >> 4;
        float S0 = (q == 0) ? kk : (q == 1) ? b1 : (q == 2) ? b2 : b3;
        float S1 = (q == 0) ? b1 : (q == 1) ? kk : (q == 2) ? b3 : b2;
        float S2 = (q == 0) ? b2 : (q == 1) ? b3 : (q == 2) ? kk : b1;
        float S3 = (q == 0) ? b3 : (q == 1) ? b2 : (q == 2) ? b1 : kk;
        float dotA[RPW] = {S0, S1};
        float dotB[RPW] = {S2, S3};

        // ---- 4 hypotheses: (d = P[u-1] branch, c = P[u] branch) ----
        float m_[2][2][RPW];
        bool  sp_[2][2][RPW];
        #pragma unroll
        for (int r = 0; r < RPW; ++r) {
            float sa = memA[r] + dotA[r];          // reference op order
            float sb = memB[r] + dotB[r];
            m_[0][0][r] = fmaxf(sa, 0.0f);
            m_[0][1][r] = fmaxf(sa - PROHIB_F, 0.0f);
            m_[1][0][r] = fmaxf(sb, 0.0f);
            m_[1][1][r] = fmaxf(sb - PROHIB_F, 0.0f);
            sp_[0][0][r] = m_[0][0][r] >= VTHR_F;
            sp_[0][1][r] = m_[0][1][r] >= VTHR_F;
            sp_[1][0][r] = m_[1][0][r] >= VTHR_F;
            sp_[1][1][r] = m_[1][1][r] >= VTHR_F;
        }
        int hb = 0;
        if (sp_[0][0][0] || sp_[0][0][1]) hb |= 1;   // k=(0<<1)|0
        if (sp_[0][1][0] || sp_[0][1][1]) hb |= 2;   // k=(0<<1)|1
        if (sp_[1][0][0] || sp_[1][0][1]) hb |= 4;   // k=(1<<1)|0
        if (sp_[1][1][0] || sp_[1][1][1]) hb |= 8;   // k=(1<<1)|1
        if (lane == 0) sh_h[u & 1][wave] = hb;

        // ---- wave0: resolve P[u-1] from line(u-2) (before the barrier) ----
        if (wave == 0) {
            int bstar = 0;
            if (u >= 2) {
                bool ok = ((gv & 0xF0u) == 0xB0u);   // lanes>=NBLK pass (gv=0xB0)
                while (!__all(ok)) {
                    if (lane < NBLK)
                        gv = __hip_atomic_load(&gl[lane], __ATOMIC_RELAXED,
                                               __HIP_MEMORY_SCOPE_AGENT);
                    ok = ((gv & 0xF0u) == 0xB0u);
                }
                uint32_t vm = (lane < NBLK) ? gv : 0u;
                int k = (p3 << 1) | p2;              // wave-uniform
                bstar = __any((int)((vm >> k) & 1u));
            }
            p3 = p2; p2 = bstar;
            if (lane == 0) sh_b[u & 1] = bstar;
        }
        __syncthreads();                             // single barrier per step

        // ---- wave0 lane0: publish this step's 4 hypothesis bits ----
        if (wave == 0 && lane == 0) {
            int hh = sh_h[u & 1][0] | sh_h[u & 1][1] | sh_h[u & 1][2] |
                     sh_h[u & 1][3] | sh_h[u & 1][4] | sh_h[u & 1][5] |
                     sh_h[u & 1][6] | sh_h[u & 1][7];
            __hip_atomic_store(&slots[(size_t)u * NBLK + blk],
                               0xB0u | (uint32_t)hh,
                               __ATOMIC_RELAXED, __HIP_MEMORY_SCOPE_AGENT);
        }
        const int bst = sh_b[u & 1];                 // resolved P[u-1]

        // ---- collapse branch d=bst; emit out(u-1); rebranch over c=P[u] ----
        bool sprv[RPW], sc0[RPW], sc1[RPW];
        float mc0[RPW], mc1[RPW];
        #pragma unroll
        for (int r = 0; r < RPW; ++r) {
            sprv[r] = bst ? psB[r] : psA[r];         // actual spike(u-1)
            sc0[r]  = bst ? sp_[1][0][r] : sp_[0][0][r];
            sc1[r]  = bst ? sp_[1][1][r] : sp_[0][1][r];
            mc0[r]  = bst ? m_[1][0][r]  : m_[0][0][r];
            mc1[r]  = bst ? m_[1][1][r]  : m_[0][1][r];
        }
        if (u >= 1 && lane == 0)
            *(float2*)(out + (size_t)(u - 1) * COUT + row0) =
                make_float2(sprv[0] ? 1.0f : 0.0f, sprv[1] ? 1.0f : 0.0f);

        #pragma unroll
        for (int r = 0; r < RPW; ++r) {
            memA[r] = sc0[r] ? 0.0f : mc0[r];
            memB[r] = sc1[r] ? 0.0f : mc1[r];
        }
        if (bst) {                                   // collapse weights to wSel
            #pragma unroll
            for (int r = 0; r < RPW; ++r)
                #pragma unroll
                for (int j = 0; j < CPL; ++j) wA[r][j] = wB[r][j];
        }
        #pragma unroll
        for (int r = 0; r < RPW; ++r) {
            // branch c=1 into wB (from collapsed wA)
            if (sc1[r]) {
                #pragma unroll
                for (int j = 0; j < CPL; ++j)
                    wB[r][j] = fminf(wA[r][j] + pf[j], 127.0f);
            } else if (sprv[r]) {
                #pragma unroll
                for (int j = 0; j < CPL; ++j)
                    wB[r][j] = fmaxf(wA[r][j] - xf[j], 0.0f);
            } else {
                #pragma unroll
                for (int j = 0; j < CPL; ++j) wB[r][j] = wA[r][j];
            }
            // branch c=0 in place into wA
            if (sc0[r]) {
                #pragma unroll
                for (int j = 0; j < CPL; ++j)
                    wA[r][j] = fminf(wA[r][j] + pf[j], 127.0f);
            } else if (sprv[r]) {
                #pragma unroll
                for (int j = 0; j < CPL; ++j)
                    wA[r][j] = fmaxf(wA[r][j] - xf[j], 0.0f);
            }
            psA[r] = sc0[r];
            psB[r] = sc1[r];
        }

        uint4 cw2 = (u + 2 < T_STEPS) ? code4[(size_t)(u + 2) * 64 + lane]
                                      : make_uint4(0u, 0u, 0u, 0u);
        cw = cwn; cwn = cw2;
    }

    // ---- epilogue: resolve P[T-1] and write out(T-1) ----
    {
        if (wave == 0) {
            const uint32_t* gl2 = slots + (size_t)(T_STEPS - 2) * NBLK;
            uint32_t gv2 = 0xB0u;
            bool ok;
            do {
                if (lane < NBLK)
                    gv2 = __hip_atomic_load(&gl2[lane], __ATOMIC_RELAXED,
                                            __HIP_MEMORY_SCOPE_AGENT);
                ok = ((gv2 & 0xF0u) == 0xB0u);
            } while (!__all(ok));
            uint32_t vm = (lane < NBLK) ? gv2 : 0u;
            int k = (p3 << 1) | p2;
            int cst = __any((int)((vm >> k) & 1u));
            if (lane == 0) sh_b[T_STEPS & 1] = cst;
        }
        __syncthreads();
        int cst = sh_b[T_STEPS & 1];
        if (lane == 0) {
            bool s0r = cst ? psB[0] : psA[0];
            bool s1r = cst ? psB[1] : psA[1];
            *(float2*)(out + (size_t)(T_STEPS - 1) * COUT + row0) =
                make_float2(s0r ? 1.0f : 0.0f, s1r ? 1.0f : 0.0f);
        }
    }
}

extern "C" void kernel_launch(void* const* d_in, const int* in_sizes, int n_in,
                              void* d_out, int out_size, void* d_ws, size_t ws_size,
                              hipStream_t stream) {
    const int*   x      = (const int*)d_in[0];     // (T,1,CIN) int32
    const float* weight = (const float*)d_in[1];   // (COUT,CIN) f32
    float* out = (float*)d_out;                    // (T,1,COUT) f32

    uint32_t* slots = (uint32_t*)d_ws;
    uint8_t*  code  = (uint8_t*)d_ws + CODE_OFFSET;

    int prep_threads = T_STEPS * 64;
    prep_kernel<<<(prep_threads + 255) / 256, 256, 0, stream>>>(x, code, slots);
    snn_kernel<<<NBLK, WPB * 64, 0, stream>>>(weight, code, slots, out);
}